// Round 1
// baseline (740.016 us; speedup 1.0000x reference)
//
#include <hip/hip_runtime.h>
#include <hip/hip_bf16.h>

// ContrastiveLoss: z (8192x1024 fp32) -> scalar
//   zn = z / max(||z||,eps); S = zn@zn^T; diag=MASK; /T; nll = -S[i,i^4096] + lse(S[i,:]); mean
// R8: MX-scaled fp8 MFMA (mfma_scale_f32_16x16x128_f8f6f4, unit e8m0 scales =
// exact same arithmetic as plain fp8, 2x the rate). The 8-VGPR A/B operand is
// the concat of the two b128 K-permuted fragment reads R7 already did (logical
// chunks kg, kg+4 = 32 contiguous bytes of the lane's K-group); K-permutation
// stays valid (dot order-invariant, uniform across lanes, same for A and B,
// all scales equal). Geometry (128B rows, chunk^(row&7) swizzle, quarter-wave
// b128) is R4's measured-0-conflict layout, unchanged. Epilogue unchanged
// (C/D layout is shape-determined: f32x4 per 16x16 tile).
// Also: k_normalize rewritten wave-per-row (no block barriers, coalesced).

#define N 8192
#define D 1024
#define INV_T 14.285714285714286f
#define NTILES 528
#define ACC_SCALE (INV_T / 1024.0f)  // undo fp8 x32 scaling on both operands

typedef float f32x4 __attribute__((ext_vector_type(4)));
typedef int i32x4 __attribute__((ext_vector_type(4)));
typedef int i32x8 __attribute__((ext_vector_type(8)));

#define UNIT_SCALE 0x7f7f7f7f  // e8m0 bias 127 -> 2^0 in every byte

__device__ inline void gload16(const void* g, void* l) {
  __builtin_amdgcn_global_load_lds(
      (const __attribute__((address_space(1))) void*)g,
      (__attribute__((address_space(3))) void*)l, 16, 0, 0);
}

// Phase 1: row-normalize z, scale x32, cast fp8 e4m3 -> zn8; zero rowsum.
// One wave per row; grid = N/4 blocks of 256 threads (4 waves).
__global__ __launch_bounds__(256) void k_normalize(const float* __restrict__ z,
                                                   unsigned char* __restrict__ zn8,
                                                   float* __restrict__ rowsum) {
  const int gt = blockIdx.x * 256 + threadIdx.x;
  if (gt < N) rowsum[gt] = 0.0f;
  const int row = gt >> 6;
  const int l = threadIdx.x & 63;
  const float4* zr = (const float4*)(z + (size_t)row * D);
  float4 v[4];
  float ss = 0.f;
#pragma unroll
  for (int j = 0; j < 4; ++j) {
    v[j] = zr[l + 64 * j];  // coalesced: lane-consecutive 16B
    ss += v[j].x * v[j].x + v[j].y * v[j].y + v[j].z * v[j].z + v[j].w * v[j].w;
  }
#pragma unroll
  for (int off = 32; off > 0; off >>= 1) ss += __shfl_xor(ss, off, 64);
  const float sc = 32.0f / fmaxf(sqrtf(ss), 1e-8f);  // e4m3 range; undone by ACC_SCALE
  int* orow = (int*)(zn8 + (size_t)row * D);
#pragma unroll
  for (int j = 0; j < 4; ++j) {
    int p = __builtin_amdgcn_cvt_pk_fp8_f32(v[j].x * sc, v[j].y * sc, 0, false);
    p = __builtin_amdgcn_cvt_pk_fp8_f32(v[j].z * sc, v[j].w * sc, p, true);
    orow[l + 64 * j] = p;  // coalesced 4B stores, same element order as loads
  }
}

// Phase 2: 256x256 lower-triangle tile per block, 512 threads (8 waves, 4x2).
// fp8 BK=128: per buffer A 32KB + B 32KB; double-buffered = 128KB dynamic LDS.
__global__ __launch_bounds__(512, 2) void k_tile(const unsigned char* __restrict__ zn8,
                                                 float* __restrict__ rowsum,
                                                 float* __restrict__ pos) {
  extern __shared__ __align__(16) char smem[];  // 131072
  const int tid = threadIdx.x;
  const int w = tid >> 6, l = tid & 63;

  // decode blockIdx -> lower-triangle (tr, tc), tr >= tc, over 32x32 tile grid
  const int b = blockIdx.x;
  int tr = (int)((sqrtf(8.0f * (float)b + 1.0f) - 1.0f) * 0.5f);
  if (tr * (tr + 1) / 2 > b) --tr;
  if ((tr + 1) * (tr + 2) / 2 <= b) ++tr;
  const int tc = b - tr * (tr + 1) / 2;
  const bool diag = (tr == tc);

  const int wr = w >> 1, wc = w & 1;
  const int m = l & 15, kg = l >> 4;
  const int rowA0 = tr * 256, colB0 = tc * 256;

  f32x4 acc[4][8] = {};

  // staging: per matrix per stage 2048 slots x 16B (256 rows x 8 chunks).
  // phys slot s -> row s>>3; phys chunk s&7 holds logical chunk (s&7)^(row&7).
  int srow[4], scol[4];
#pragma unroll
  for (int j = 0; j < 4; ++j) {
    int s = j * 512 + tid;
    int r = s >> 3;
    srow[j] = r;
    scol[j] = (s & 7) ^ (r & 7);
  }

  // fragment reads: logical chunks kg and kg+4 (K-permuted; A/B identical).
  // Together: 32 bytes = the lane's full K-group for the K=128 MX MFMA.
  const int csw0 = (kg ^ (m & 7)) * 16;
  const int csw1 = ((kg + 4) ^ (m & 7)) * 16;

  // prologue: stage kt=0 into buffer 0
  {
    char* ab = smem;
    char* bb = smem + 32768;
#pragma unroll
    for (int j = 0; j < 4; ++j) {
      const int s = j * 512 + tid;
      gload16((const char*)zn8 + ((size_t)(rowA0 + srow[j]) * D + scol[j] * 16), ab + s * 16);
    }
    if (!diag) {
#pragma unroll
      for (int j = 0; j < 4; ++j) {
        const int s = j * 512 + tid;
        gload16((const char*)zn8 + ((size_t)(colB0 + srow[j]) * D + scol[j] * 16), bb + s * 16);
      }
    }
  }
  __syncthreads();

  for (int kt = 0; kt < 8; ++kt) {
    if (kt < 7) {  // async prefetch kt+1 into other buffer; overlaps MFMA below
      const size_t kb = (size_t)(kt + 1) * 128;
      char* ab = smem + ((kt + 1) & 1) * 65536;
#pragma unroll
      for (int j = 0; j < 4; ++j) {
        const int s = j * 512 + tid;
        gload16((const char*)zn8 + ((size_t)(rowA0 + srow[j]) * D + kb + scol[j] * 16), ab + s * 16);
      }
      if (!diag) {
        char* bb = ab + 32768;
#pragma unroll
        for (int j = 0; j < 4; ++j) {
          const int s = j * 512 + tid;
          gload16((const char*)zn8 + ((size_t)(colB0 + srow[j]) * D + kb + scol[j] * 16), bb + s * 16);
        }
      }
    }
    const char* ab = smem + (kt & 1) * 65536;
    const char* bb = diag ? ab : (ab + 32768);

    i32x8 af[4];
#pragma unroll
    for (int mt = 0; mt < 4; ++mt) {
      const char* rp = ab + (wr * 64 + mt * 16 + m) * 128;
      const i32x4 lo = *(const i32x4*)(rp + csw0);
      const i32x4 hi = *(const i32x4*)(rp + csw1);
      af[mt] = __builtin_shufflevector(lo, hi, 0, 1, 2, 3, 4, 5, 6, 7);
    }
#pragma unroll
    for (int nt = 0; nt < 8; ++nt) {
      const char* rp = bb + (wc * 128 + nt * 16 + m) * 128;
      const i32x4 lo = *(const i32x4*)(rp + csw0);
      const i32x4 hi = *(const i32x4*)(rp + csw1);
      const i32x8 bf = __builtin_shufflevector(lo, hi, 0, 1, 2, 3, 4, 5, 6, 7);
#pragma unroll
      for (int mt = 0; mt < 4; ++mt) {
        acc[mt][nt] = __builtin_amdgcn_mfma_scale_f32_16x16x128_f8f6f4(
            af[mt], bf, acc[mt][nt], 0, 0,  // cbsz=0 (fp8 e4m3), blgp=0 (fp8 e4m3)
            0, UNIT_SCALE, 0, UNIT_SCALE);  // unit block scales: exact fp8 GEMM
      }
    }
    __syncthreads();  // drains prefetch (vmcnt) + guards buffer reuse
  }

  // Epilogue. C/D layout: col=l&15, row=(l>>4)*4+reg (shape-determined, same as R7).
  const int quad = l >> 4;
  const int col = l & 15;
  float cs[8] = {0.f, 0.f, 0.f, 0.f, 0.f, 0.f, 0.f, 0.f};
#pragma unroll
  for (int mt = 0; mt < 4; ++mt) {
    float rs[4] = {0.f, 0.f, 0.f, 0.f};
#pragma unroll
    for (int nt = 0; nt < 8; ++nt) {
      const int gcol = colB0 + wc * 128 + nt * 16 + col;
#pragma unroll
      for (int r = 0; r < 4; ++r) {
        const int grow = rowA0 + wr * 64 + mt * 16 + quad * 4 + r;
        const float t = acc[mt][nt][r] * ACC_SCALE;
        if (gcol == (grow ^ (N / 2))) {  // pos pair; never in diag tiles
          pos[grow] = t;
          pos[gcol] = t;  // S symmetric
        }
        const float e = (gcol == grow) ? 0.0f : __expf(t - INV_T);
        rs[r] += e;
        cs[nt] += e;
      }
    }
#pragma unroll
    for (int off = 1; off < 16; off <<= 1) {
#pragma unroll
      for (int r = 0; r < 4; ++r) rs[r] += __shfl_xor(rs[r], off, 64);
    }
    if (col == 0) {
#pragma unroll
      for (int r = 0; r < 4; ++r)
        atomicAdd(&rowsum[rowA0 + wr * 64 + mt * 16 + quad * 4 + r], rs[r]);
    }
  }
  if (!diag) {  // col sums = row-sums for block tc rows (symmetry)
#pragma unroll
    for (int nt = 0; nt < 8; ++nt) {
      cs[nt] += __shfl_xor(cs[nt], 16, 64);
      cs[nt] += __shfl_xor(cs[nt], 32, 64);
    }
    if (l < 16) {
#pragma unroll
      for (int nt = 0; nt < 8; ++nt)
        atomicAdd(&rowsum[colB0 + wc * 128 + nt * 16 + l], cs[nt]);
    }
  }
}

// Phase 3: single block: out = mean(-pos + C + log(rowsum)).
__global__ __launch_bounds__(1024) void k_final(const float* __restrict__ rowsum,
                                                const float* __restrict__ pos,
                                                float* __restrict__ out) {
  const int t = threadIdx.x;
  float s = 0.f;
  for (int i = t; i < N; i += 1024) s += INV_T + __logf(rowsum[i]) - pos[i];
#pragma unroll
  for (int off = 32; off > 0; off >>= 1) s += __shfl_down(s, off, 64);
  __shared__ float red[16];
  if ((t & 63) == 0) red[t >> 6] = s;
  __syncthreads();
  if (t == 0) {
    float tot = 0.f;
#pragma unroll
    for (int j = 0; j < 16; ++j) tot += red[j];
    out[0] = tot * (1.0f / N);
  }
}

extern "C" void kernel_launch(void* const* d_in, const int* in_sizes, int n_in,
                              void* d_out, int out_size, void* d_ws, size_t ws_size,
                              hipStream_t stream) {
  const float* z = (const float*)d_in[0];
  float* out = (float*)d_out;
  char* ws = (char*)d_ws;
  unsigned char* zn8 = (unsigned char*)ws;                    // 8 MiB fp8
  float* rowsum = (float*)(ws + (size_t)N * D);               // 32 KiB
  float* pos = (float*)(ws + (size_t)N * D + (size_t)N * 4);  // 32 KiB

  static bool attr_set = false;
  if (!attr_set) {  // host-side attribute, idempotent, not a stream op
    hipFuncSetAttribute((const void*)k_tile,
                        hipFuncAttributeMaxDynamicSharedMemorySize, 131072);
    attr_set = true;
  }

  k_normalize<<<N / 4, 256, 0, stream>>>(z, zn8, rowsum);
  k_tile<<<NTILES, 512, 131072, stream>>>(zn8, rowsum, pos);
  k_final<<<1, 1024, 0, stream>>>(rowsum, pos, out);
}

// Round 2
// 334.521 us; speedup vs baseline: 2.2122x; 2.2122x over previous
//
#include <hip/hip_runtime.h>
#include <hip/hip_bf16.h>

// ContrastiveLoss: z (8192x1024 fp32) -> scalar
//   zn = z / max(||z||,eps); S = zn@zn^T; diag=MASK; /T; nll = -S[i,i^4096] + lse(S[i,:]); mean
// R9: back to proven plain fp8 e4m3 16x16x32 MFMA (R8's MX mfma_scale spilled
// ~2.3KB/thread to scratch: WRITE_SIZE 6MB->624MB). New lever: BK=64 K-stages
// -> 32KB/stage, double-buffered 64KB LDS -> 2 blocks/CU co-resident (was 1 at
// 128KB). Co-residency fills each block's per-stage barrier/vmcnt drain (~39%
// of cycles in R7: MfmaUtil 37.6 + VALUBusy 23.7) and cuts the dispatch tail
// from 2.06 to ~1.03 rounds. Swizzle re-derived for 64B rows: phys chunk =
// c ^ ((row>>1)&3); per quarter-wave the 16 lanes map bijectively onto the 8
// bank-groups of the 128B wrap (2 lanes each = conflict-free). K-permuted
// fragment reads as before: lane reads one b128 at logical chunk kg; step s
// uses the s-th 8-byte half; A/B share the permutation (dot K-order-invariant).

#define N 8192
#define D 1024
#define INV_T 14.285714285714286f
#define NTILES 528
#define ACC_SCALE (INV_T / 1024.0f)  // undo fp8 x32 scaling on both operands

typedef float f32x4 __attribute__((ext_vector_type(4)));
typedef long lx2 __attribute__((ext_vector_type(2)));

__device__ inline void gload16(const void* g, void* l) {
  __builtin_amdgcn_global_load_lds(
      (const __attribute__((address_space(1))) void*)g,
      (__attribute__((address_space(3))) void*)l, 16, 0, 0);
}

// Phase 1: row-normalize z, scale x32, cast fp8 e4m3 -> zn8; zero rowsum.
// One wave per row; grid = N/4 blocks of 256 threads (4 waves).
__global__ __launch_bounds__(256) void k_normalize(const float* __restrict__ z,
                                                   unsigned char* __restrict__ zn8,
                                                   float* __restrict__ rowsum) {
  const int gt = blockIdx.x * 256 + threadIdx.x;
  if (gt < N) rowsum[gt] = 0.0f;
  const int row = gt >> 6;
  const int l = threadIdx.x & 63;
  const float4* zr = (const float4*)(z + (size_t)row * D);
  float4 v[4];
  float ss = 0.f;
#pragma unroll
  for (int j = 0; j < 4; ++j) {
    v[j] = zr[l + 64 * j];  // coalesced: lane-consecutive 16B
    ss += v[j].x * v[j].x + v[j].y * v[j].y + v[j].z * v[j].z + v[j].w * v[j].w;
  }
#pragma unroll
  for (int off = 32; off > 0; off >>= 1) ss += __shfl_xor(ss, off, 64);
  const float sc = 32.0f / fmaxf(sqrtf(ss), 1e-8f);  // e4m3 range; undone by ACC_SCALE
  int* orow = (int*)(zn8 + (size_t)row * D);
#pragma unroll
  for (int j = 0; j < 4; ++j) {
    int p = __builtin_amdgcn_cvt_pk_fp8_f32(v[j].x * sc, v[j].y * sc, 0, false);
    p = __builtin_amdgcn_cvt_pk_fp8_f32(v[j].z * sc, v[j].w * sc, p, true);
    orow[l + 64 * j] = p;  // coalesced 4B stores, same element order as loads
  }
}

// Phase 2: 256x256 lower-triangle tile per block, 512 threads (8 waves, 4x2).
// fp8 BK=64: per stage A 16KB + B 16KB; double-buffered = 64KB dynamic LDS
// -> 2 blocks/CU.
__global__ __launch_bounds__(512, 4) void k_tile(const unsigned char* __restrict__ zn8,
                                                 float* __restrict__ rowsum,
                                                 float* __restrict__ pos) {
  extern __shared__ __align__(16) char smem[];  // 65536
  const int tid = threadIdx.x;
  const int w = tid >> 6, l = tid & 63;

  // decode blockIdx -> lower-triangle (tr, tc), tr >= tc, over 32x32 tile grid
  const int b = blockIdx.x;
  int tr = (int)((sqrtf(8.0f * (float)b + 1.0f) - 1.0f) * 0.5f);
  if (tr * (tr + 1) / 2 > b) --tr;
  if ((tr + 1) * (tr + 2) / 2 <= b) ++tr;
  const int tc = b - tr * (tr + 1) / 2;
  const bool diag = (tr == tc);

  const int wr = w >> 1, wc = w & 1;
  const int m = l & 15, kg = l >> 4;
  const int rowA0 = tr * 256, colB0 = tc * 256;

  f32x4 acc[4][8] = {};

  // staging: per matrix per stage 1024 slots x 16B (256 rows x 4 chunks).
  // phys slot s -> row s>>2; phys chunk s&3 holds logical chunk (s&3)^((r>>1)&3).
  int srow[2], scol[2];
#pragma unroll
  for (int j = 0; j < 2; ++j) {
    int s = j * 512 + tid;
    int r = s >> 2;
    srow[j] = r;
    scol[j] = (s & 3) ^ ((r >> 1) & 3);
  }

  // fragment read: logical chunk kg (K-permuted; A/B identical).
  // 16B = both K32 steps of the BK=64 stage (step s = s-th 8-byte half).
  const int csw = (kg ^ ((m >> 1) & 3)) * 16;

  // prologue: stage kt=0 into buffer 0
  {
    char* ab = smem;
    char* bb = smem + 16384;
#pragma unroll
    for (int j = 0; j < 2; ++j) {
      const int s = j * 512 + tid;
      gload16((const char*)zn8 + ((size_t)(rowA0 + srow[j]) * D + scol[j] * 16), ab + s * 16);
    }
    if (!diag) {
#pragma unroll
      for (int j = 0; j < 2; ++j) {
        const int s = j * 512 + tid;
        gload16((const char*)zn8 + ((size_t)(colB0 + srow[j]) * D + scol[j] * 16), bb + s * 16);
      }
    }
  }
  __syncthreads();

  for (int kt = 0; kt < 16; ++kt) {
    if (kt < 15) {  // async prefetch kt+1 into other buffer; overlaps MFMA below
      const size_t kb = (size_t)(kt + 1) * 64;
      char* ab = smem + ((kt + 1) & 1) * 32768;
#pragma unroll
      for (int j = 0; j < 2; ++j) {
        const int s = j * 512 + tid;
        gload16((const char*)zn8 + ((size_t)(rowA0 + srow[j]) * D + kb + scol[j] * 16), ab + s * 16);
      }
      if (!diag) {
        char* bb = ab + 16384;
#pragma unroll
        for (int j = 0; j < 2; ++j) {
          const int s = j * 512 + tid;
          gload16((const char*)zn8 + ((size_t)(colB0 + srow[j]) * D + kb + scol[j] * 16), bb + s * 16);
        }
      }
    }
    const char* ab = smem + (kt & 1) * 32768;
    const char* bb = diag ? ab : (ab + 16384);

    lx2 a[4];
#pragma unroll
    for (int mt = 0; mt < 4; ++mt) {
      const char* rp = ab + (wr * 64 + mt * 16 + m) * 64;
      a[mt] = *(const lx2*)(rp + csw);
    }
#pragma unroll
    for (int nt = 0; nt < 8; ++nt) {
      const char* rp = bb + (wc * 128 + nt * 16 + m) * 64;
      const lx2 bfrag = *(const lx2*)(rp + csw);
#pragma unroll
      for (int mt = 0; mt < 4; ++mt) {
        acc[mt][nt] = __builtin_amdgcn_mfma_f32_16x16x32_fp8_fp8(a[mt].x, bfrag.x, acc[mt][nt], 0, 0, 0);
        acc[mt][nt] = __builtin_amdgcn_mfma_f32_16x16x32_fp8_fp8(a[mt].y, bfrag.y, acc[mt][nt], 0, 0, 0);
      }
    }
    __syncthreads();  // drains prefetch (vmcnt) + guards buffer reuse
  }

  // Epilogue. C/D layout: col=l&15, row=(l>>4)*4+reg.
  const int quad = l >> 4;
  const int col = l & 15;
  float cs[8] = {0.f, 0.f, 0.f, 0.f, 0.f, 0.f, 0.f, 0.f};
#pragma unroll
  for (int mt = 0; mt < 4; ++mt) {
    float rs[4] = {0.f, 0.f, 0.f, 0.f};
#pragma unroll
    for (int nt = 0; nt < 8; ++nt) {
      const int gcol = colB0 + wc * 128 + nt * 16 + col;
#pragma unroll
      for (int r = 0; r < 4; ++r) {
        const int grow = rowA0 + wr * 64 + mt * 16 + quad * 4 + r;
        const float t = acc[mt][nt][r] * ACC_SCALE;
        if (gcol == (grow ^ (N / 2))) {  // pos pair; never in diag tiles
          pos[grow] = t;
          pos[gcol] = t;  // S symmetric
        }
        const float e = (gcol == grow) ? 0.0f : __expf(t - INV_T);
        rs[r] += e;
        cs[nt] += e;
      }
    }
#pragma unroll
    for (int off = 1; off < 16; off <<= 1) {
#pragma unroll
      for (int r = 0; r < 4; ++r) rs[r] += __shfl_xor(rs[r], off, 64);
    }
    if (col == 0) {
#pragma unroll
      for (int r = 0; r < 4; ++r)
        atomicAdd(&rowsum[rowA0 + wr * 64 + mt * 16 + quad * 4 + r], rs[r]);
    }
  }
  if (!diag) {  // col sums = row-sums for block tc rows (symmetry)
#pragma unroll
    for (int nt = 0; nt < 8; ++nt) {
      cs[nt] += __shfl_xor(cs[nt], 16, 64);
      cs[nt] += __shfl_xor(cs[nt], 32, 64);
    }
    if (l < 16) {
#pragma unroll
      for (int nt = 0; nt < 8; ++nt)
        atomicAdd(&rowsum[colB0 + wc * 128 + nt * 16 + l], cs[nt]);
    }
  }
}

// Phase 3: single block: out = mean(-pos + C + log(rowsum)).
__global__ __launch_bounds__(1024) void k_final(const float* __restrict__ rowsum,
                                                const float* __restrict__ pos,
                                                float* __restrict__ out) {
  const int t = threadIdx.x;
  float s = 0.f;
  for (int i = t; i < N; i += 1024) s += INV_T + __logf(rowsum[i]) - pos[i];
#pragma unroll
  for (int off = 32; off > 0; off >>= 1) s += __shfl_down(s, off, 64);
  __shared__ float red[16];
  if ((t & 63) == 0) red[t >> 6] = s;
  __syncthreads();
  if (t == 0) {
    float tot = 0.f;
#pragma unroll
    for (int j = 0; j < 16; ++j) tot += red[j];
    out[0] = tot * (1.0f / N);
  }
}

extern "C" void kernel_launch(void* const* d_in, const int* in_sizes, int n_in,
                              void* d_out, int out_size, void* d_ws, size_t ws_size,
                              hipStream_t stream) {
  const float* z = (const float*)d_in[0];
  float* out = (float*)d_out;
  char* ws = (char*)d_ws;
  unsigned char* zn8 = (unsigned char*)ws;                    // 8 MiB fp8
  float* rowsum = (float*)(ws + (size_t)N * D);               // 32 KiB
  float* pos = (float*)(ws + (size_t)N * D + (size_t)N * 4);  // 32 KiB

  static bool attr_set = false;
  if (!attr_set) {  // host-side attribute, idempotent, not a stream op
    hipFuncSetAttribute((const void*)k_tile,
                        hipFuncAttributeMaxDynamicSharedMemorySize, 65536);
    attr_set = true;
  }

  k_normalize<<<N / 4, 256, 0, stream>>>(z, zn8, rowsum);
  k_tile<<<NTILES, 512, 65536, stream>>>(zn8, rowsum, pos);
  k_final<<<1, 1024, 0, stream>>>(rowsum, pos, out);
}

// Round 3
// 154.729 us; speedup vs baseline: 4.7826x; 2.1620x over previous
//
#include <hip/hip_runtime.h>
#include <hip/hip_bf16.h>

// ContrastiveLoss: z (8192x1024 fp32) -> scalar
//   zn = z / max(||z||,eps); S = zn@zn^T; diag=MASK; /T; nll = -S[i,i^4096] + lse(S[i,:]); mean
// R10: plain fp8 e4m3 16x16x32 MFMA (R7 numerics), but the per-stage
// __syncthreads vmcnt(0) drain (~65% of R7's stage time) is replaced by a
// 4-buffer, prefetch-distance-2 pipeline with COUNTED vmcnt (T3/T4):
//   stage kt: issue batch kt+2 -> buf[(kt+2)&3]; s_waitcnt vmcnt(8)  (batch kt
//   landed, kt+1/kt+2 stay in flight); s_barrier; compute buf[kt&3].
// WAR: slot (kt+2)&3 == (kt-2)&3 was last read before barrier(kt-1) -> safe.
// RAW: each wave counts its own loads before the barrier; barrier publishes.
// BK=64 stages (A 16KB + B 16KB = 32KB/stage, x4 = 128KB LDS). Swizzle is
// R9's verified 64B-row layout: phys chunk = c ^ ((row>>1)&3); quarter-wave
// b128 reads land 2 lanes/bank-group (free). launch_bounds(512,2) — R9's
// (512,4) caused catastrophic accumulator spill (VGPR 64, WRITE_SIZE 525MB).

#define N 8192
#define D 1024
#define INV_T 14.285714285714286f
#define NTILES 528
#define ACC_SCALE (INV_T / 1024.0f)  // undo fp8 x32 scaling on both operands

typedef float f32x4 __attribute__((ext_vector_type(4)));
typedef long lx2 __attribute__((ext_vector_type(2)));

#define WAITV(n) asm volatile("s_waitcnt vmcnt(" #n ")" ::: "memory")

__device__ inline void gload16(const void* g, void* l) {
  __builtin_amdgcn_global_load_lds(
      (const __attribute__((address_space(1))) void*)g,
      (__attribute__((address_space(3))) void*)l, 16, 0, 0);
}

// Phase 1: row-normalize z, scale x32, cast fp8 e4m3 -> zn8; zero rowsum.
// One wave per row; grid = N/4 blocks of 256 threads (4 waves).
__global__ __launch_bounds__(256) void k_normalize(const float* __restrict__ z,
                                                   unsigned char* __restrict__ zn8,
                                                   float* __restrict__ rowsum) {
  const int gt = blockIdx.x * 256 + threadIdx.x;
  if (gt < N) rowsum[gt] = 0.0f;
  const int row = gt >> 6;
  const int l = threadIdx.x & 63;
  const float4* zr = (const float4*)(z + (size_t)row * D);
  float4 v[4];
  float ss = 0.f;
#pragma unroll
  for (int j = 0; j < 4; ++j) {
    v[j] = zr[l + 64 * j];  // coalesced: lane-consecutive 16B
    ss += v[j].x * v[j].x + v[j].y * v[j].y + v[j].z * v[j].z + v[j].w * v[j].w;
  }
#pragma unroll
  for (int off = 32; off > 0; off >>= 1) ss += __shfl_xor(ss, off, 64);
  const float sc = 32.0f / fmaxf(sqrtf(ss), 1e-8f);  // e4m3 range; undone by ACC_SCALE
  int* orow = (int*)(zn8 + (size_t)row * D);
#pragma unroll
  for (int j = 0; j < 4; ++j) {
    int p = __builtin_amdgcn_cvt_pk_fp8_f32(v[j].x * sc, v[j].y * sc, 0, false);
    p = __builtin_amdgcn_cvt_pk_fp8_f32(v[j].z * sc, v[j].w * sc, p, true);
    orow[l + 64 * j] = p;  // coalesced 4B stores, same element order as loads
  }
}

// Phase 2: 256x256 lower-triangle tile per block, 512 threads (8 waves, 4x2).
// fp8 BK=64: per stage A 16KB + B 16KB; 4 buffers = 128KB dynamic LDS.
__global__ __launch_bounds__(512, 2) void k_tile(const unsigned char* __restrict__ zn8,
                                                 float* __restrict__ rowsum,
                                                 float* __restrict__ pos) {
  extern __shared__ __align__(16) char smem[];  // 131072
  const int tid = threadIdx.x;
  const int w = tid >> 6, l = tid & 63;

  // decode blockIdx -> lower-triangle (tr, tc), tr >= tc, over 32x32 tile grid
  const int b = blockIdx.x;
  int tr = (int)((sqrtf(8.0f * (float)b + 1.0f) - 1.0f) * 0.5f);
  if (tr * (tr + 1) / 2 > b) --tr;
  if ((tr + 1) * (tr + 2) / 2 <= b) ++tr;
  const int tc = b - tr * (tr + 1) / 2;
  const bool diag = (tr == tc);

  const int wr = w >> 1, wc = w & 1;
  const int m = l & 15, kg = l >> 4;
  const int rowA0 = tr * 256, colB0 = tc * 256;

  f32x4 acc[4][8] = {};

  // staging: per matrix per stage 1024 slots x 16B (256 rows x 4 chunks).
  // phys slot s -> row s>>2; phys chunk s&3 holds logical chunk (s&3)^((r>>1)&3).
  int srow[2], scol[2];
#pragma unroll
  for (int j = 0; j < 2; ++j) {
    int s = j * 512 + tid;
    int r = s >> 2;
    srow[j] = r;
    scol[j] = (s & 3) ^ ((r >> 1) & 3);
  }

  // fragment read: logical chunk kg (K-permuted; A/B identical).
  // 16B = both K32 steps of the BK=64 stage (step s = s-th 8-byte half).
  const int csw = (kg ^ ((m >> 1) & 3)) * 16;

  // prologue: stage batches 0 and 1 into buffers 0 and 1 (prefetch distance 2)
#pragma unroll
  for (int p = 0; p < 2; ++p) {
    const size_t kb = (size_t)p * 64;
    char* ab = smem + p * 32768;
    char* bb = ab + 16384;
#pragma unroll
    for (int j = 0; j < 2; ++j) {
      const int s = j * 512 + tid;
      gload16((const char*)zn8 + ((size_t)(rowA0 + srow[j]) * D + kb + scol[j] * 16), ab + s * 16);
    }
    if (!diag) {
#pragma unroll
      for (int j = 0; j < 2; ++j) {
        const int s = j * 512 + tid;
        gload16((const char*)zn8 + ((size_t)(colB0 + srow[j]) * D + kb + scol[j] * 16), bb + s * 16);
      }
    }
  }

  for (int kt = 0; kt < 16; ++kt) {
    if (kt < 14) {  // issue batch kt+2 into buf[(kt+2)&3]; stays in flight across barrier
      const size_t kb = (size_t)(kt + 2) * 64;
      char* ab = smem + ((kt + 2) & 3) * 32768;
#pragma unroll
      for (int j = 0; j < 2; ++j) {
        const int s = j * 512 + tid;
        gload16((const char*)zn8 + ((size_t)(rowA0 + srow[j]) * D + kb + scol[j] * 16), ab + s * 16);
      }
      if (!diag) {
        char* bb = ab + 16384;
#pragma unroll
        for (int j = 0; j < 2; ++j) {
          const int s = j * 512 + tid;
          gload16((const char*)zn8 + ((size_t)(colB0 + srow[j]) * D + kb + scol[j] * 16), bb + s * 16);
        }
      }
    }
    // counted wait: batch kt must have landed; batches kt+1, kt+2 stay in flight.
    // off-diag: 4 loads/batch -> 8 in flight; diag: 2 -> 4. Tail drains.
    if (!diag) {
      if (kt < 14) WAITV(8);
      else if (kt == 14) WAITV(4);
      else WAITV(0);
    } else {
      if (kt < 14) WAITV(4);
      else if (kt == 14) WAITV(2);
      else WAITV(0);
    }
    __builtin_amdgcn_s_barrier();  // publishes: all waves' batch-kt loads landed
    asm volatile("" ::: "memory");  // keep ds_reads below the barrier

    const char* ab = smem + (kt & 3) * 32768;
    const char* bb = diag ? ab : (ab + 16384);

    lx2 a[4];
#pragma unroll
    for (int mt = 0; mt < 4; ++mt) {
      const char* rp = ab + (wr * 64 + mt * 16 + m) * 64;
      a[mt] = *(const lx2*)(rp + csw);
    }
#pragma unroll
    for (int nt = 0; nt < 8; ++nt) {
      const char* rp = bb + (wc * 128 + nt * 16 + m) * 64;
      const lx2 bfrag = *(const lx2*)(rp + csw);
#pragma unroll
      for (int mt = 0; mt < 4; ++mt) {
        acc[mt][nt] = __builtin_amdgcn_mfma_f32_16x16x32_fp8_fp8(a[mt].x, bfrag.x, acc[mt][nt], 0, 0, 0);
        acc[mt][nt] = __builtin_amdgcn_mfma_f32_16x16x32_fp8_fp8(a[mt].y, bfrag.y, acc[mt][nt], 0, 0, 0);
      }
    }
    // no end-of-stage barrier: next stage's top barrier provides WAR protection
  }

  // Epilogue. C/D layout: col=l&15, row=(l>>4)*4+reg.
  const int quad = l >> 4;
  const int col = l & 15;
  float cs[8] = {0.f, 0.f, 0.f, 0.f, 0.f, 0.f, 0.f, 0.f};
#pragma unroll
  for (int mt = 0; mt < 4; ++mt) {
    float rs[4] = {0.f, 0.f, 0.f, 0.f};
#pragma unroll
    for (int nt = 0; nt < 8; ++nt) {
      const int gcol = colB0 + wc * 128 + nt * 16 + col;
#pragma unroll
      for (int r = 0; r < 4; ++r) {
        const int grow = rowA0 + wr * 64 + mt * 16 + quad * 4 + r;
        const float t = acc[mt][nt][r] * ACC_SCALE;
        if (gcol == (grow ^ (N / 2))) {  // pos pair; never in diag tiles
          pos[grow] = t;
          pos[gcol] = t;  // S symmetric
        }
        const float e = (gcol == grow) ? 0.0f : __expf(t - INV_T);
        rs[r] += e;
        cs[nt] += e;
      }
    }
#pragma unroll
    for (int off = 1; off < 16; off <<= 1) {
#pragma unroll
      for (int r = 0; r < 4; ++r) rs[r] += __shfl_xor(rs[r], off, 64);
    }
    if (col == 0) {
#pragma unroll
      for (int r = 0; r < 4; ++r)
        atomicAdd(&rowsum[rowA0 + wr * 64 + mt * 16 + quad * 4 + r], rs[r]);
    }
  }
  if (!diag) {  // col sums = row-sums for block tc rows (symmetry)
#pragma unroll
    for (int nt = 0; nt < 8; ++nt) {
      cs[nt] += __shfl_xor(cs[nt], 16, 64);
      cs[nt] += __shfl_xor(cs[nt], 32, 64);
    }
    if (l < 16) {
#pragma unroll
      for (int nt = 0; nt < 8; ++nt)
        atomicAdd(&rowsum[colB0 + wc * 128 + nt * 16 + l], cs[nt]);
    }
  }
}

// Phase 3: single block: out = mean(-pos + C + log(rowsum)).
__global__ __launch_bounds__(1024) void k_final(const float* __restrict__ rowsum,
                                                const float* __restrict__ pos,
                                                float* __restrict__ out) {
  const int t = threadIdx.x;
  float s = 0.f;
  for (int i = t; i < N; i += 1024) s += INV_T + __logf(rowsum[i]) - pos[i];
#pragma unroll
  for (int off = 32; off > 0; off >>= 1) s += __shfl_down(s, off, 64);
  __shared__ float red[16];
  if ((t & 63) == 0) red[t >> 6] = s;
  __syncthreads();
  if (t == 0) {
    float tot = 0.f;
#pragma unroll
    for (int j = 0; j < 16; ++j) tot += red[j];
    out[0] = tot * (1.0f / N);
  }
}

extern "C" void kernel_launch(void* const* d_in, const int* in_sizes, int n_in,
                              void* d_out, int out_size, void* d_ws, size_t ws_size,
                              hipStream_t stream) {
  const float* z = (const float*)d_in[0];
  float* out = (float*)d_out;
  char* ws = (char*)d_ws;
  unsigned char* zn8 = (unsigned char*)ws;                    // 8 MiB fp8
  float* rowsum = (float*)(ws + (size_t)N * D);               // 32 KiB
  float* pos = (float*)(ws + (size_t)N * D + (size_t)N * 4);  // 32 KiB

  static bool attr_set = false;
  if (!attr_set) {  // host-side attribute, idempotent, not a stream op
    hipFuncSetAttribute((const void*)k_tile,
                        hipFuncAttributeMaxDynamicSharedMemorySize, 131072);
    attr_set = true;
  }

  k_normalize<<<N / 4, 256, 0, stream>>>(z, zn8, rowsum);
  k_tile<<<NTILES, 512, 131072, stream>>>(zn8, rowsum, pos);
  k_final<<<1, 1024, 0, stream>>>(rowsum, pos, out);
}